// Round 1
// baseline (226.549 us; speedup 1.0000x reference)
//
#include <hip/hip_runtime.h>
#include <stdint.h>

#define Bb 8
#define Nn 16384
#define Cc 40
#define Ee 512
#define Dd 256

typedef __attribute__((ext_vector_type(4))) float f32x4;
typedef __attribute__((ext_vector_type(8))) short bf16x8;

__device__ __forceinline__ unsigned short f2bf(float f) {
  union { float f; uint32_t u; } x; x.f = f;
  uint32_t r = x.u + 0x7FFFu + ((x.u >> 16) & 1u);   // round-to-nearest-even
  return (unsigned short)(r >> 16);
}
__device__ __forceinline__ unsigned int pack2(float a, float b) {
  return (unsigned int)f2bf(a) | ((unsigned int)f2bf(b) << 16);
}

// ---------------- P1a: kp[f][bc] = dot(Wk[f,:], k[bc,:]) + bk[f] ----------------
// grid (40,4) = (bc-groups of 8, f-groups of 128); 256 threads
__global__ __launch_bounds__(256) void p1a_kernel(
    const float* __restrict__ k, const float* __restrict__ Wk,
    const float* __restrict__ bk, float* __restrict__ kp) {
  __shared__ float lds_k[8][Dd];
  const int t = threadIdx.x;
  const int bcg = blockIdx.x, fg = blockIdx.y;
  for (int i = t; i < 8 * Dd; i += 256) {
    int row = i >> 8, d = i & (Dd - 1);
    lds_k[row][d] = k[(size_t)(bcg * 8 + row) * Dd + d];
  }
  __syncthreads();
  const int f = fg * 128 + (t & 127);
  const int half = t >> 7;
  const float* wrow = Wk + (size_t)f * Dd;
  float a0 = 0, a1 = 0, a2 = 0, a3 = 0;
  #pragma unroll 4
  for (int d = 0; d < Dd; d += 4) {
    float4 w  = *(const float4*)(wrow + d);
    float4 k0 = *(const float4*)&lds_k[half*4+0][d];
    float4 k1 = *(const float4*)&lds_k[half*4+1][d];
    float4 k2 = *(const float4*)&lds_k[half*4+2][d];
    float4 k3 = *(const float4*)&lds_k[half*4+3][d];
    a0 += w.x*k0.x + w.y*k0.y + w.z*k0.z + w.w*k0.w;
    a1 += w.x*k1.x + w.y*k1.y + w.z*k1.z + w.w*k1.w;
    a2 += w.x*k2.x + w.y*k2.y + w.z*k2.z + w.w*k2.w;
    a3 += w.x*k3.x + w.y*k3.y + w.z*k3.z + w.w*k3.w;
  }
  const float bkf = bk[f];
  float acc[4] = {a0, a1, a2, a3};
  #pragma unroll
  for (int ii = 0; ii < 4; ii++)
    kp[(size_t)f * 320 + bcg*8 + half*4 + ii] = acc[ii] + bkf;
}

// ---------------- P1b: G[e][bc] = scale * dot(Wq[:,e], kp[:,bc]) -> A-fragments;
//                  dbias[bc] = scale * dot(bq, kp[:,bc]) ----------------
// grid (40,4) = (bc-groups, e-groups of 128); 256 threads
__global__ __launch_bounds__(256) void p1b_kernel(
    const float* __restrict__ kp, const float* __restrict__ Wq,
    const float* __restrict__ bq, unsigned short* __restrict__ abfrag,
    float* __restrict__ dbias) {
  __shared__ float lds_kp[64][8];
  __shared__ float lds_bq[64];
  const int t = threadIdx.x;
  const int bcg = blockIdx.x, eg = blockIdx.y;
  const int e = eg * 128 + (t & 127);
  const int half = t >> 7;
  const float scale = 0.044194173824159216f;  // 1/sqrt(512)
  float acc[4] = {0,0,0,0};
  float dpart = 0.f;
  for (int f0 = 0; f0 < Ee; f0 += 64) {
    __syncthreads();
    for (int i = t; i < 512; i += 256) {
      int ff = i >> 3, bcl = i & 7;
      lds_kp[ff][bcl] = kp[(size_t)(f0 + ff) * 320 + bcg*8 + bcl];
    }
    if (t < 64) lds_bq[t] = bq[f0 + t];
    __syncthreads();
    #pragma unroll 8
    for (int ff = 0; ff < 64; ff++) {
      float wq = Wq[(size_t)(f0 + ff) * Ee + e];   // coalesced across lanes
      float4 kv = *(const float4*)&lds_kp[ff][half*4];
      acc[0] += wq * kv.x; acc[1] += wq * kv.y;
      acc[2] += wq * kv.z; acc[3] += wq * kv.w;
    }
    if (eg == 0 && t < 8) {
      float s = 0;
      for (int ff = 0; ff < 64; ff++) s += lds_bq[ff] * lds_kp[ff][t];
      dpart += s;
    }
  }
  if (eg == 0 && t < 8) {
    int bc = bcg*8 + t;
    dbias[(bc / Cc)*64 + (bc % Cc)] = scale * dpart;
  }
  // scatter into MFMA A-operand layout: lane holds A[row=l&15, k=8*(l>>4)+j]
  const int ks = e >> 5, gg = (e >> 3) & 3, j = e & 7;
  #pragma unroll
  for (int ii = 0; ii < 4; ii++) {
    int bc = bcg*8 + half*4 + ii;
    int b = bc / Cc, c = bc % Cc;
    int ct = c >> 4;
    int lane = (c & 15) + 16*gg;
    abfrag[((((size_t)b*3 + ct)*16 + ks)*64 + lane)*8 + j] = f2bf(scale * acc[ii]);
  }
}

// ---------------- P2: vp[bc][e] = dot(Wv[e,:], v[bc,:]) + bv[e] -> B-fragments ----
// grid (40,4); 256 threads
__global__ __launch_bounds__(256) void p2_kernel(
    const float* __restrict__ v, const float* __restrict__ Wv,
    const float* __restrict__ bv, unsigned short* __restrict__ vpfrag) {
  __shared__ float lds_v[8][Dd];
  const int t = threadIdx.x;
  const int bcg = blockIdx.x, eg = blockIdx.y;
  for (int i = t; i < 8 * Dd; i += 256) {
    int row = i >> 8, d = i & (Dd - 1);
    lds_v[row][d] = v[(size_t)(bcg * 8 + row) * Dd + d];
  }
  __syncthreads();
  const int e = eg * 128 + (t & 127);
  const int half = t >> 7;
  const float* wrow = Wv + (size_t)e * Dd;
  float acc[4] = {0,0,0,0};
  #pragma unroll 4
  for (int d = 0; d < Dd; d += 4) {
    float4 w = *(const float4*)(wrow + d);
    #pragma unroll
    for (int ii = 0; ii < 4; ii++) {
      float4 kv = *(const float4*)&lds_v[half*4+ii][d];
      acc[ii] += w.x*kv.x + w.y*kv.y + w.z*kv.z + w.w*kv.w;
    }
  }
  const float bve = bv[e];
  const int nt = e >> 4, el = e & 15;
  #pragma unroll
  for (int ii = 0; ii < 4; ii++) {
    int bc = bcg*8 + half*4 + ii;
    int b = bc / Cc, c = bc % Cc;
    int s = c >> 5, gg = (c >> 3) & 3, j = c & 7;
    int lane = el + 16*gg;
    vpfrag[((((size_t)b*32 + nt)*2 + s)*64 + lane)*8 + j] = f2bf(acc[ii] + bve);
  }
}

// ---------------- main: fused logits -> softmax -> *cp -> softmax -> PV ----------
// grid 2048 (= B * N/64); 256 threads = 4 independent waves; wave owns 16 q-rows
__global__ __launch_bounds__(256) void main_kernel(
    const float* __restrict__ q, const float* __restrict__ coarse,
    const unsigned short* __restrict__ abfrag,
    const unsigned short* __restrict__ vpfrag,
    const float* __restrict__ dbias, float* __restrict__ out) {
  __shared__ unsigned short s_att[4][16][72];   // 72 = 64 + 8 pad (bank decorrelation)
  const int t = threadIdx.x;
  const int wave = t >> 6, lane = t & 63;
  const int r = lane & 15, g = lane >> 4;
  const int bid = blockIdx.x;
  const int b = bid >> 8, nb = bid & 255;
  const int nw = nb * 64 + wave * 16;
  const float* qrow = q + ((size_t)b * Nn + nw + r) * Ee;
  const bf16x8* abf = (const bf16x8*)abfrag + (size_t)b * 3 * 16 * 64 + lane;

  // ---- logits (swapped: D[c, r] = G^T · q^T), K = 512 ----
  f32x4 acc0 = {0,0,0,0}, acc1 = {0,0,0,0}, acc2 = {0,0,0,0};
  #pragma unroll
  for (int ks = 0; ks < 16; ks++) {
    float4 q0 = *(const float4*)(qrow + 32*ks + 8*g);
    float4 q1 = *(const float4*)(qrow + 32*ks + 8*g + 4);
    bf16x8 qf;
    qf[0] = (short)f2bf(q0.x); qf[1] = (short)f2bf(q0.y);
    qf[2] = (short)f2bf(q0.z); qf[3] = (short)f2bf(q0.w);
    qf[4] = (short)f2bf(q1.x); qf[5] = (short)f2bf(q1.y);
    qf[6] = (short)f2bf(q1.z); qf[7] = (short)f2bf(q1.w);
    acc0 = __builtin_amdgcn_mfma_f32_16x16x32_bf16(abf[(0*16+ks)*64], qf, acc0, 0,0,0);
    acc1 = __builtin_amdgcn_mfma_f32_16x16x32_bf16(abf[(1*16+ks)*64], qf, acc1, 0,0,0);
    acc2 = __builtin_amdgcn_mfma_f32_16x16x32_bf16(abf[(2*16+ks)*64], qf, acc2, 0,0,0);
  }

  // lane holds logits of q-row (nw+r) at classes c = 16*ct + 4*g + reg
  float L[3][4];
  #pragma unroll
  for (int rg = 0; rg < 4; rg++) {
    L[0][rg] = acc0[rg] + dbias[b*64 +  0 + 4*g + rg];
    L[1][rg] = acc1[rg] + dbias[b*64 + 16 + 4*g + rg];
    L[2][rg] = acc2[rg] + dbias[b*64 + 32 + 4*g + rg];
  }
  const bool v2 = (g < 2);   // ct==2 slots valid only when 32+4g+reg < 40

  // ---- softmax #1 over c (row spread across lanes r, r+16, r+32, r+48) ----
  float m1 = -3e38f;
  #pragma unroll
  for (int rg = 0; rg < 4; rg++) {
    m1 = fmaxf(m1, L[0][rg]); m1 = fmaxf(m1, L[1][rg]);
    if (v2) m1 = fmaxf(m1, L[2][rg]);
  }
  m1 = fmaxf(m1, __shfl_xor(m1, 16));
  m1 = fmaxf(m1, __shfl_xor(m1, 32));
  float p[3][4]; float s1 = 0.f;
  #pragma unroll
  for (int rg = 0; rg < 4; rg++) {
    p[0][rg] = __expf(L[0][rg] - m1); s1 += p[0][rg];
    p[1][rg] = __expf(L[1][rg] - m1); s1 += p[1][rg];
    p[2][rg] = v2 ? __expf(L[2][rg] - m1) : 0.f; s1 += p[2][rg];
  }
  s1 += __shfl_xor(s1, 16); s1 += __shfl_xor(s1, 32);
  const float inv1 = 1.0f / s1;

  // ---- cp = softmax_c(coarse_pred[b, c, n]) in the same lane layout ----
  const float* cbase = coarse + (size_t)b * Cc * Nn + (nw + r);
  float cr[3][4];
  #pragma unroll
  for (int rg = 0; rg < 4; rg++) {
    cr[0][rg] = cbase[(size_t)( 0 + 4*g + rg) * Nn];
    cr[1][rg] = cbase[(size_t)(16 + 4*g + rg) * Nn];
    cr[2][rg] = v2 ? cbase[(size_t)(32 + 4*g + rg) * Nn] : -3e38f;
  }
  float m2 = -3e38f;
  #pragma unroll
  for (int rg = 0; rg < 4; rg++) {
    m2 = fmaxf(m2, cr[0][rg]); m2 = fmaxf(m2, cr[1][rg]);
    if (v2) m2 = fmaxf(m2, cr[2][rg]);
  }
  m2 = fmaxf(m2, __shfl_xor(m2, 16));
  m2 = fmaxf(m2, __shfl_xor(m2, 32));
  float cpv[3][4]; float s2 = 0.f;
  #pragma unroll
  for (int rg = 0; rg < 4; rg++) {
    cpv[0][rg] = __expf(cr[0][rg] - m2); s2 += cpv[0][rg];
    cpv[1][rg] = __expf(cr[1][rg] - m2); s2 += cpv[1][rg];
    cpv[2][rg] = v2 ? __expf(cr[2][rg] - m2) : 0.f; s2 += cpv[2][rg];
  }
  s2 += __shfl_xor(s2, 16); s2 += __shfl_xor(s2, 32);
  const float inv2 = 1.0f / s2;

  // ---- softmax #2 over c of (attn1 * cp) ----
  const float sc12 = inv1 * inv2;
  float w[3][4];
  float m3 = -3e38f;
  #pragma unroll
  for (int rg = 0; rg < 4; rg++) {
    w[0][rg] = p[0][rg] * cpv[0][rg] * sc12;
    w[1][rg] = p[1][rg] * cpv[1][rg] * sc12;
    w[2][rg] = v2 ? (p[2][rg] * cpv[2][rg] * sc12) : 0.f;
    m3 = fmaxf(m3, w[0][rg]); m3 = fmaxf(m3, w[1][rg]);
    if (v2) m3 = fmaxf(m3, w[2][rg]);
  }
  m3 = fmaxf(m3, __shfl_xor(m3, 16));
  m3 = fmaxf(m3, __shfl_xor(m3, 32));
  float p3[3][4]; float s3 = 0.f;
  #pragma unroll
  for (int rg = 0; rg < 4; rg++) {
    p3[0][rg] = __expf(w[0][rg] - m3); s3 += p3[0][rg];
    p3[1][rg] = __expf(w[1][rg] - m3); s3 += p3[1][rg];
    p3[2][rg] = v2 ? __expf(w[2][rg] - m3) : 0.f; s3 += p3[2][rg];
  }
  s3 += __shfl_xor(s3, 16); s3 += __shfl_xor(s3, 32);
  const float inv3 = 1.0f / s3;

  // ---- re-fragment attn2 via per-wave LDS round-trip (no barrier needed) ----
  unsigned int* srow = (unsigned int*)&s_att[wave][r][0];
  #pragma unroll
  for (int ct = 0; ct < 3; ct++) {
    srow[8*ct + 2*g + 0] = pack2(p3[ct][0]*inv3, p3[ct][1]*inv3);
    srow[8*ct + 2*g + 1] = pack2(p3[ct][2]*inv3, p3[ct][3]*inv3);
  }
  srow[24 + 2*g + 0] = 0u;   // c = 48..63 zero pad
  srow[24 + 2*g + 1] = 0u;
  asm volatile("s_waitcnt lgkmcnt(0)" ::: "memory");
  const bf16x8 pa0 = *(const bf16x8*)&s_att[wave][r][ 0 + 8*g];
  const bf16x8 pa1 = *(const bf16x8*)&s_att[wave][r][32 + 8*g];

  // ---- PV: out[16 x 512] = attn2[16 x 64] @ vp[64 x 512] ----
  const bf16x8* vpf = (const bf16x8*)vpfrag + (size_t)b * 32 * 2 * 64 + lane;
  float* outb = out + ((size_t)b * Nn + nw) * Ee;
  #pragma unroll 8
  for (int nt = 0; nt < 32; nt++) {
    bf16x8 vf0 = vpf[(nt*2 + 0)*64];
    bf16x8 vf1 = vpf[(nt*2 + 1)*64];
    f32x4 o = {0,0,0,0};
    o = __builtin_amdgcn_mfma_f32_16x16x32_bf16(pa0, vf0, o, 0,0,0);
    o = __builtin_amdgcn_mfma_f32_16x16x32_bf16(pa1, vf1, o, 0,0,0);
    #pragma unroll
    for (int rg = 0; rg < 4; rg++)
      outb[(size_t)(4*g + rg) * Ee + nt*16 + r] = o[rg];
  }
}

extern "C" void kernel_launch(void* const* d_in, const int* in_sizes, int n_in,
                              void* d_out, int out_size, void* d_ws, size_t ws_size,
                              hipStream_t stream) {
  const float* q   = (const float*)d_in[0];
  const float* k   = (const float*)d_in[1];
  const float* v   = (const float*)d_in[2];
  const float* cps = (const float*)d_in[3];
  const float* Wq  = (const float*)d_in[4];
  const float* bq  = (const float*)d_in[5];
  const float* Wk  = (const float*)d_in[6];
  const float* bk  = (const float*)d_in[7];
  const float* Wv  = (const float*)d_in[8];
  const float* bv  = (const float*)d_in[9];
  float* out = (float*)d_out;
  char* ws = (char*)d_ws;

  // ws layout
  float*          kp    = (float*)(ws);                               // 512*320*4   = 655360
  unsigned short* abf   = (unsigned short*)(ws + 655360);             // 8*3*16*64*8*2 = 393216
  unsigned short* vpf   = (unsigned short*)(ws + 655360 + 393216);    // 8*32*2*64*8*2 = 524288
  float*          dbias = (float*)(ws + 655360 + 393216 + 524288);    // 8*64*4 = 2048

  hipMemsetAsync(ws + 655360, 0, 393216 + 524288 + 2048, stream);
  p1a_kernel<<<dim3(40, 4), 256, 0, stream>>>(k, Wk, bk, kp);
  p1b_kernel<<<dim3(40, 4), 256, 0, stream>>>(kp, Wq, bq, abf, dbias);
  p2_kernel <<<dim3(40, 4), 256, 0, stream>>>(v, Wv, bv, vpf);
  main_kernel<<<dim3(2048), 256, 0, stream>>>(q, cps, abf, vpf, dbias, out);
}